// Round 9
// baseline (1169.943 us; speedup 1.0000x reference)
//
#include <hip/hip_runtime.h>
#include <math.h>

#define BATCH 256
typedef unsigned int uint;
typedef unsigned short ushort;
typedef _Float16 half8 __attribute__((ext_vector_type(8)));
typedef float f32x4 __attribute__((ext_vector_type(4)));
typedef uint u32x4 __attribute__((ext_vector_type(4)));

#define GLOBAL_AS __attribute__((address_space(1)))
#define LDS_AS __attribute__((address_space(3)))

__device__ __forceinline__ ushort f2h(float f) {
  _Float16 h = (_Float16)f;
  return __builtin_bit_cast(ushort, h);
}

// x fp32 [256][18^4] -> xw f16 windowed [t18][d18][h18][wt3][b256][8] (FW=5)
__global__ __launch_bounds__(256) void transpose_win(
    const float* __restrict__ x, ushort* __restrict__ xw) {
  const int P = 104976;  // 18^4
  __shared__ float tile[64][65];
  int p0 = blockIdx.x * 64, b0 = blockIdx.y * 64;
  int tx = threadIdx.x & 63, ty = threadIdx.x >> 6;
#pragma unroll
  for (int r = 0; r < 64; r += 4) {
    int pp = p0 + tx;
    if (pp < P) tile[tx][ty + r] = x[(size_t)(b0 + ty + r) * P + pp];
  }
  __syncthreads();
#pragma unroll
  for (int r = 0; r < 64; r += 4) {
    int pl = ty + r, pp = p0 + pl;
    if (pp < P) {
      ushort hv = f2h(tile[pl][tx]);
      int w = pp % 18;
      int rest = pp / 18;
      int h = rest % 18; rest /= 18;
      int d = rest % 18;
      int t = rest / 18;
      size_t rowb = ((((size_t)t * 18 + d) * 18 + h) * 3) * 2048;
#pragma unroll
      for (int wt = 0; wt < 3; wt++) {
        int wi = w - wt * 5;
        if (wi >= 0 && wi < 8)
          xw[rowb + (size_t)wt * 2048 + (size_t)(b0 + tx) * 8 + wi] = hv;
      }
    }
  }
}

// Block-Toeplitz B table: Bg[c][nblk=3][n16][k32] f16.
// c = s*NR+cg, s=(ci,kt,kd). k=(rr,wi): row=cg*4+rr. n=(dh*FW+dw)*COUT+co.
// B = w[co][ci][kt][kd][row-dh][wi-dw] when valid else 0.
template <int CIN, int COUT, int KK, int FH, int FW, int NR>
__global__ __launch_bounds__(256) void build_b(
    const float* __restrict__ w, ushort* __restrict__ Bg) {
  const int c = blockIdx.x;
  const int cg = c % NR, s = c / NR;
  const int kd = s % KK, kt = (s / KK) % KK, ci = s / (KK * KK);
  for (int e = threadIdx.x; e < 3 * 512; e += 256) {
    int nblk = e / 512, rem = e % 512, n16 = rem >> 5, k = rem & 31;
    int n = nblk * 16 + n16;
    int rr = k >> 3, wi = k & 7, row = cg * 4 + rr;
    float v = 0.f;
    if (n < FH * FW * COUT) {
      int dh = n / (FW * COUT), r2 = n % (FW * COUT);
      int dw = r2 / COUT, co = r2 % COUT;
      int kh = row - dh, kw = wi - dw;
      if (kh >= 0 && kh < KK && kw >= 0 && kw < KK)
        v = w[((((co * CIN + ci) * KK + kt) * KK + kd) * KK + kh) * KK + kw];
    }
    Bg[(size_t)(c * 3 + nblk) * 512 + n16 * 32 + k] = f2h(v);
  }
}

// MFMA implicit conv, Toeplitz h+w fold. In: windowed f16
// [ci][TI][TI][TI][NWT_IN][b][8]; out: windowed for next layer (or PLAIN
// [co][WO^4][b] for fc1). M=batch(256), N=48=(dh,dw,co) x 3 blocks,
// K-chunks of 32=(row rr x wi8) per (ci,kt,kd) slab (NR groups).
// A-frag = ONE ds_read_b128 (wi-contiguous layout; R7 lesson: 8x ds_read_u16
// was 4-way bank-conflicted). A-frag reused across 3 N-blocks.
// R8 lesson: pad rows >= RS are READ (zero-B x A); they must be FULLY zeroed
// — one row = 256 u32x4, not 128. Half-zeroed rows left NaN garbage ->
// 0*NaN = NaN poisoned whole accumulator rows (relu squashed them to 0).
template <int CIN, int COUT, int KK, int TI, int FH, int FW, int NWT_IN,
          int FWN, int NWTN, bool PLAIN>
__global__ __launch_bounds__(256) void conv_mfma(
    const ushort* __restrict__ xin, const ushort* __restrict__ Bg,
    const float* __restrict__ bias, ushort* __restrict__ out) {
  constexpr int WO = TI - KK + 1;
  constexpr int HTILES = WO / FH;
  constexpr int RS = FH + KK - 1;       // staged input h-rows
  constexpr int NR = (RS + 3) / 4;      // K-chunk groups per slab
  constexpr int NC = CIN * KK * KK;     // slabs
  constexpr int NFOLD = FH * FW * COUT; // valid N columns (<=48)
  constexpr int sH = NWT_IN * 2048;
  constexpr int sD = TI * sH, sT = TI * sD, sC = TI * sT;

  __shared__ __attribute__((aligned(16))) ushort slab[2][8 * 2048];

  const int ht = blockIdx.x % HTILES;
  const int wt = blockIdx.x / HTILES;
  const int d = blockIdx.y, t = blockIdx.z;
  const int h0 = ht * FH, wb = wt * FW;
  const int tid = threadIdx.x, wave = tid >> 6, lane = tid & 63;
  const int quad = lane >> 4, mm = lane & 15;

  // FULLY zero pad rows >= RS in both buffers (one row = 2048 ushorts =
  // 256 u32x4). These rows are read by the last chunk group under zero-B.
  if (RS < 8) {
#pragma unroll
    for (int bb = 0; bb < 2; bb++)
      for (int i = tid; i < (8 - RS) * 256; i += 256)
        ((u32x4*)(void*)(&slab[bb][RS * 2048]))[i] = (u32x4){0, 0, 0, 0};
  }

  auto stage = [&](int s, int buf) {
    const int kd = s % KK, kt = (s / KK) % KK, ci = s / (KK * KK);
    const ushort* base =
        xin + (size_t)ci * sC + (size_t)(t + kt) * sT + (size_t)(d + kd) * sD +
        (size_t)wt * 2048;
    for (int r = wave; r < RS; r += 4) {  // strictly in-bounds: h0+r <= TI-1
      const ushort* g = base + (size_t)(h0 + r) * sH;
      ushort* l = &slab[buf][r * 2048];
#pragma unroll
      for (int p = 0; p < 4; p++) {
        __builtin_amdgcn_global_load_lds(
            (const GLOBAL_AS uint*)(const void*)(g + p * 512 + lane * 8),
            (LDS_AS uint*)(void*)(l + p * 512), 16, 0, 0);
      }
    }
  };

  f32x4 acc[3][4];
#pragma unroll
  for (int nb = 0; nb < 3; nb++)
#pragma unroll
    for (int bt = 0; bt < 4; bt++) acc[nb][bt] = (f32x4){0.f, 0.f, 0.f, 0.f};

  stage(0, 0);

#pragma unroll 1
  for (int s = 0; s < NC; s++) {
    __syncthreads();  // vmcnt(0) drain: slab[s&1] ready, slab[(s+1)&1] free
    if (s + 1 < NC) stage(s + 1, (s + 1) & 1);
    const int buf = s & 1;
#pragma unroll
    for (int cg = 0; cg < NR; cg++) {
      const int c = s * NR + cg;
      u32x4 braw[3];
#pragma unroll
      for (int nb = 0; nb < 3; nb++)
        braw[nb] = *(const u32x4*)(const void*)(
            Bg + (size_t)(c * 3 + nb) * 512 + mm * 32 + quad * 8);
#pragma unroll
      for (int bt = 0; bt < 4; bt++) {
        const ushort* ap =
            &slab[buf][(cg * 4 + quad) * 2048 + (wave * 64 + bt * 16 + mm) * 8];
        half8 af = *(const half8*)(const void*)ap;  // one ds_read_b128
#pragma unroll
        for (int nb = 0; nb < 3; nb++)
          acc[nb][bt] = __builtin_amdgcn_mfma_f32_16x16x32_f16(
              af, __builtin_bit_cast(half8, braw[nb]), acc[nb][bt], 0, 0, 0);
      }
    }
  }

  // Epilogue. C/D: n = lane&15 (+16*nblk), batch m = quad*4+reg (verified R7).
#pragma unroll
  for (int nb = 0; nb < 3; nb++) {
    const int n = nb * 16 + mm;
    if (n < NFOLD) {
      const int dh = n / (FW * COUT), r2 = n % (FW * COUT);
      const int dw = r2 / COUT, co = r2 % COUT;
      const int h = h0 + dh, w = wb + dw;
      const float bv = bias[co];
#pragma unroll
      for (int bt = 0; bt < 4; bt++) {
#pragma unroll
        for (int reg = 0; reg < 4; reg++) {
          const int b = wave * 64 + bt * 16 + quad * 4 + reg;
          float v = acc[nb][bt][reg] + bv;
          v = v > 0.f ? v : 0.f;
          ushort hv = f2h(v);
          if (PLAIN) {
            out[(((((size_t)co * WO + t) * WO + d) * WO + h) * WO + w) * BATCH +
                b] = hv;
          } else {
            const size_t rowb =
                ((((size_t)co * WO + t) * WO + d) * WO + h) * NWTN * 2048;
#pragma unroll
            for (int wt2 = 0; wt2 < NWTN; wt2++) {
              int wi = w - wt2 * FWN;
              if (wi >= 0 && wi < 8)
                out[rowb + (size_t)wt2 * 2048 + (size_t)b * 8 + wi] = hv;
            }
          }
        }
      }
    }
  }
}

// h5 f16 plain [1280][256] (k=co,t,d,h,w). One block per output neuron.
__global__ __launch_bounds__(256) void fc1_kernel(
    const ushort* __restrict__ h, const float* __restrict__ w,
    const float* __restrict__ bias, float* __restrict__ out) {
  const int o = blockIdx.x, b = threadIdx.x;
  const float* wr = w + o * 1280;
  float a0 = 0.f, a1 = 0.f, a2 = 0.f, a3 = 0.f;
#pragma unroll 4
  for (int k = 0; k < 1280; k += 4) {
    a0 = fmaf((float)__builtin_bit_cast(_Float16, h[(k + 0) * BATCH + b]), wr[k + 0], a0);
    a1 = fmaf((float)__builtin_bit_cast(_Float16, h[(k + 1) * BATCH + b]), wr[k + 1], a1);
    a2 = fmaf((float)__builtin_bit_cast(_Float16, h[(k + 2) * BATCH + b]), wr[k + 2], a2);
    a3 = fmaf((float)__builtin_bit_cast(_Float16, h[(k + 3) * BATCH + b]), wr[k + 3], a3);
  }
  float acc = (a0 + a1) + (a2 + a3) + bias[o];
  out[o * BATCH + b] = acc > 0.f ? acc : 0.f;
}

__global__ __launch_bounds__(256) void fc2_kernel(
    const float* __restrict__ r, const float* __restrict__ w,
    const float* __restrict__ bias, float* __restrict__ out) {
  const int b = threadIdx.x;
  float acc = bias[0];
#pragma unroll
  for (int o = 0; o < 33; o++) acc = fmaf(r[o * BATCH + b], w[o], acc);
  out[b] = 1.f / (1.f + expf(-acc));
}

extern "C" void kernel_launch(void* const* d_in, const int* in_sizes, int n_in,
                              void* d_out, int out_size, void* d_ws, size_t ws_size,
                              hipStream_t stream) {
  const float* x    = (const float*)d_in[0];
  const float* w1   = (const float*)d_in[1];
  const float* b1   = (const float*)d_in[2];
  const float* w2   = (const float*)d_in[3];
  const float* b2   = (const float*)d_in[4];
  const float* w3   = (const float*)d_in[5];
  const float* b3   = (const float*)d_in[6];
  const float* w4   = (const float*)d_in[7];
  const float* b4   = (const float*)d_in[8];
  const float* w5   = (const float*)d_in[9];
  const float* b5   = (const float*)d_in[10];
  const float* fc1w = (const float*)d_in[11];
  const float* fc1b = (const float*)d_in[12];
  const float* fc2w = (const float*)d_in[13];
  const float* fc2b = (const float*)d_in[14];
  float* out = (float*)d_out;

  // Workspace (ushort units). Windowed activations; h3/h4/h5 reuse xw's region
  // (xw dead by conv3; stale bytes there are finite f16 -> NaN-safe under
  // zero-B pad slots). Total <= 262.3 MB.
  ushort* wsu = (ushort*)d_ws;
  ushort* xw = wsu;                    // 35,831,808 u (18^3*3*2048)
  ushort* h3 = wsu;                    // 11,943,936 u (4*9^3*2*2048)
  ushort* h4 = wsu + 12000000;         //  2,211,840 u (5*6^3*1*2048)
  ushort* h5 = wsu + 15000000;         //    327,680 u (5*256*256) PLAIN
  ushort* h1 = wsu + 36000000;         // 62,208,000 u (3*15^3*3*2048)
  ushort* h2 = wsu + 98500000;         // 31,850,496 u (3*12^3*3*2048)
  ushort* Bgb = wsu + 130400000;       // 397*1536 = 609,792 u
  float* fo = (float*)(wsu + 131100000);

  ushort* B1 = Bgb;                    // 32 chunks * 1536
  ushort* B2 = Bgb + (size_t)32 * 1536;   // 96
  ushort* B3 = Bgb + (size_t)128 * 1536;  // 96
  ushort* B4 = Bgb + (size_t)224 * 1536;  // 128
  ushort* B5 = Bgb + (size_t)352 * 1536;  // 45

  // <CIN,COUT,KK,FH,FW,NR>, grid = NC*NR chunks
  build_b<1, 3, 4, 3, 5, 2><<<32, 256, 0, stream>>>(w1, B1);
  build_b<3, 3, 4, 4, 4, 2><<<96, 256, 0, stream>>>(w2, B2);
  build_b<3, 4, 4, 3, 3, 2><<<96, 256, 0, stream>>>(w3, B3);
  build_b<4, 5, 4, 3, 3, 2><<<128, 256, 0, stream>>>(w4, B4);
  build_b<5, 5, 3, 2, 4, 1><<<45, 256, 0, stream>>>(w5, B5);

  transpose_win<<<dim3(1641, 4), 256, 0, stream>>>(x, xw);

  // <CIN,COUT,KK,TI,FH,FW,NWT_IN,FWN,NWTN,PLAIN> grid(ht+HTILES*wt, d, t)
  conv_mfma<1, 3, 4, 18, 3, 5, 3, 4, 3, false>
      <<<dim3(15, 15, 15), 256, 0, stream>>>(xw, B1, b1, h1);
  conv_mfma<3, 3, 4, 15, 4, 4, 3, 3, 3, false>
      <<<dim3(9, 12, 12), 256, 0, stream>>>(h1, B2, b2, h2);
  conv_mfma<3, 4, 4, 12, 3, 3, 3, 3, 2, false>
      <<<dim3(9, 9, 9), 256, 0, stream>>>(h2, B3, b3, h3);
  conv_mfma<4, 5, 4, 9, 3, 3, 2, 4, 1, false>
      <<<dim3(4, 6, 6), 256, 0, stream>>>(h3, B4, b4, h4);
  conv_mfma<5, 5, 3, 6, 2, 4, 1, 1, 1, true>
      <<<dim3(2, 4, 4), 256, 0, stream>>>(h4, B5, b5, h5);

  fc1_kernel<<<33, 256, 0, stream>>>(h5, fc1w, fc1b, fo);
  fc2_kernel<<<1, 256, 0, stream>>>(fo, fc2w, fc2b, out);
}